// Round 1
// baseline (61.370 us; speedup 1.0000x reference)
//
#include <hip/hip_runtime.h>

// DenseByItems: out[b,k] = dot(V[items[b,k]], seq[b]) + B[items[b,k]]
// seq: [4096,128] f32, items: [4096,200] i32, V: [100000,128] f32, B: [100000] f32
// out: [4096,200] f32

#define BATCH 4096
#define KITEMS 200
#define DIM 128

__global__ __launch_bounds__(256, 4) void dense_by_items_kernel(
    const float* __restrict__ seq,    // [BATCH, DIM]
    const int*   __restrict__ items,  // [BATCH, KITEMS]
    const float* __restrict__ V,      // [NUM_ITEMS, DIM]
    const float* __restrict__ Bias,   // [NUM_ITEMS]
    float*       __restrict__ out)    // [BATCH, KITEMS]
{
    const int b    = blockIdx.x;
    const int tid  = threadIdx.x;
    const int lane = tid & 63;
    const int wave = tid >> 6;   // 0..3
    const int sub  = lane & 15;  // position within 16-lane group
    const int grp  = lane >> 4;  // 0..3 (which item within the wave's 4)

    __shared__ int s_items[KITEMS];
    if (tid < KITEMS) s_items[tid] = items[b * KITEMS + tid];
    __syncthreads();

    // Each lane owns 8 contiguous seq elements: [sub*8, sub*8+8)
    const float4* seq4 = reinterpret_cast<const float4*>(seq + b * DIM);
    const float4 s0 = seq4[sub * 2 + 0];
    const float4 s1 = seq4[sub * 2 + 1];

    // Wave w handles items k0..k0+3 with k0 = 4*w + 16*i.
    // k = k0 + grp <= 196 + 3 = 199 < KITEMS always, so no tail guard needed,
    // but keep one for safety if KITEMS changes.
    for (int k0 = wave * 4; k0 < KITEMS; k0 += 16) {
        const int k = k0 + grp;
        float p = 0.0f;
        int item = 0;
        const bool active = (k < KITEMS);
        if (active) {
            item = s_items[k];  // broadcast within 16-lane group
            const float4* v4 = reinterpret_cast<const float4*>(V + (size_t)item * DIM);
            const float4 v0 = v4[sub * 2 + 0];
            const float4 v1 = v4[sub * 2 + 1];
            p = s0.x * v0.x + s0.y * v0.y + s0.z * v0.z + s0.w * v0.w
              + s1.x * v1.x + s1.y * v1.y + s1.z * v1.z + s1.w * v1.w;
        }
        // Reduce across the 16-lane group (offsets stay within the group).
        p += __shfl_xor(p, 1);
        p += __shfl_xor(p, 2);
        p += __shfl_xor(p, 4);
        p += __shfl_xor(p, 8);
        if (active && sub == 0) {
            out[b * KITEMS + k] = p + Bias[item];
        }
    }
}

extern "C" void kernel_launch(void* const* d_in, const int* in_sizes, int n_in,
                              void* d_out, int out_size, void* d_ws, size_t ws_size,
                              hipStream_t stream) {
    const float* seq   = (const float*)d_in[0];
    const int*   items = (const int*)d_in[1];
    const float* V     = (const float*)d_in[2];
    const float* Bias  = (const float*)d_in[3];
    float*       out   = (float*)d_out;

    dense_by_items_kernel<<<dim3(BATCH), dim3(256), 0, stream>>>(seq, items, V, Bias, out);
}